// Round 12
// baseline (479.882 us; speedup 1.0000x reference)
//
#include <hip/hip_runtime.h>

typedef _Float16 h8 __attribute__((ext_vector_type(8)));
typedef _Float16 h4 __attribute__((ext_vector_type(4)));
typedef float f32x4 __attribute__((ext_vector_type(4)));

union HU { _Float16 h; unsigned short u; };
__device__ __forceinline__ unsigned short f2h(float f) { HU x; x.h = (_Float16)f; return x.u; }
__device__ __forceinline__ float h2f(unsigned short u) { HU x; x.u = u; return (float)x.h; }

#define MFMA16(a, b, c) __builtin_amdgcn_mfma_f32_16x16x32_f16((a), (b), (c), 0, 0, 0)

// ---------------------------------------------------------------------------
// k_prep: UNCHANGED from round 11 (validated).
// ---------------------------------------------------------------------------
__global__ void k_prep(const float* __restrict__ w1, const float* __restrict__ w2,
                       const float* __restrict__ w3,
                       const float* __restrict__ ptw1, const float* __restrict__ cfw1,
                       const float* __restrict__ ptw2, const float* __restrict__ ptw3,
                       const float* __restrict__ cfw2,
                       unsigned short* __restrict__ w1f,
                       unsigned short* __restrict__ w2f,
                       unsigned short* __restrict__ w3f,
                       unsigned short* __restrict__ w1hd,
                       unsigned short* __restrict__ w2hd,
                       unsigned short* __restrict__ w3hd) {
    int gid = blockIdx.x * 256 + threadIdx.x;
    int gs = gridDim.x * 256;
    for (int e = gid; e < 1024; e += gs) {
        int f = e >> 9, lane = (e >> 3) & 63, j = e & 7;
        int k = ((lane >> 4) << 3) + j, oc = lane & 15;
        int r, within;
        if (f == 0) { r = k >> 4; within = k & 15; }
        else        { r = 2;      within = k; }
        int tx = within >> 2, ch = within & 3;
        float v = 0.f;
        if (tx < 3 && ch < 3) v = w1[oc * 27 + ch * 9 + r * 3 + tx];
        w1f[e] = f2h(v);
    }
    for (int e = gid; e < 9216; e += gs) {
        int j = e & 7, lane = (e >> 3) & 63, fo = e >> 9;   // fo = t*2+ot
        int ot = fo & 1, t = fo >> 1;
        int k = ((lane >> 4) * 8) + j, oc = ot * 16 + (lane & 15);
        float v = (k < 16) ? w2[oc * 144 + k * 9 + t] : 0.f;
        w2f[e] = f2h(v);
    }
    for (int e = gid; e < 18432; e += gs) {
        int j = e & 7, lane = (e >> 3) & 63, fo = e >> 9;   // fo = (otp*9+t)*2+oti
        int oti = fo & 1, t = (fo >> 1) % 9, otp = (fo >> 1) / 9;
        int ic = ((lane >> 4) * 8) + j, oc = (otp * 2 + oti) * 16 + (lane & 15);
        w3f[e] = f2h(w3[oc * 288 + ic * 9 + t]);
    }
    for (int s = gid; s < 608 * 192; s += gs) {
        int k = s / 192, n = s - k * 192;
        float v = 0.f;
        if (k < 584) {
            int f = (k < 576) ? ((k & 63) * 9 + (k >> 6)) : k;
            v = (n < 128) ? ptw1[f * 128 + n] : cfw1[f * 64 + (n - 128)];
        }
        int kk = k >> 5, hi = (k & 31) >> 3, j = k & 7, nt = n >> 4;
        int e = (((kk * 12 + nt) << 6) | (hi << 4) | (n & 15)) << 3 | j;
        w1hd[e] = f2h(v);
    }
    for (int s = gid; s < 8192; s += gs) {
        int k = s >> 6, n = s & 63;
        float v = ptw2[k * 64 + n];
        int kk = k >> 5, hi = (k & 31) >> 3, j = k & 7, nt = n >> 4;
        int e = ((((kk << 2) | nt) << 6) | (hi << 4) | (n & 15)) << 3 | j;
        w2hd[e] = f2h(v);
    }
    for (int e = gid; e < 2048; e += gs) {
        int j = e & 7, lane = (e >> 3) & 63, kk = e >> 9;
        int k = kk * 32 + ((lane >> 4) * 8) + j, n = lane & 15;
        float v = 0.f;
        if (k < 64) { if (n < 2) v = ptw3[k * 2 + n]; }
        else        { if (n == 2) v = cfw2[k - 64]; }
        w3hd[e] = f2h(v);
    }
}

// ---------------------------------------------------------------------------
// k_fused: 16-sample blocks (4 waves), 27.0 KB LDS -> 6 blocks/CU.
// Overlay map (halfwords):
//   A1 @0 (16x584=9344) -> A2 overlay @0 (16x296) -> FT overlay @0 (16x616=9856)
//   BD @9344 (16x260=4160; dead after conv1)
//   H  @9856 (16x200=3200; inside dead BD/FT-free zone, live during L1..L3)
//   O  @13056 (64 f32 = 128 hw)
//   LDSTOT 13504 hw = 27008 B
// Splits: conv1 pos 9/wave; conv2 (ot=wid&1, y 0-3 | 4-5); conv3 (otp=wid&1,
// pos 0-4 | 5-8); L1 3 nt/wave; L2 nt=wid; L3 wave 0.
// ---------------------------------------------------------------------------
#define A1S 584
#define A2S 296
#define FTS 616
#define BDS4 260
#define BD_OFF 9344
#define H_OFF 9856
#define HSH 200
#define O_OFF 13056
#define LDSTOT 13504

template<int OT, int Y0, int Y1>
__device__ __forceinline__ void conv2_sweep(
    const unsigned short* LDSH, const h8* W2r, float b2v,
    int q, int col, f32x4* pooled2)
{
    const f32x4 ZERO4 = {0.f, 0.f, 0.f, 0.f};
    const int sA1 = col * A1S;
    const int kho = (q & 1) * 8;
    h8 R[3][6];
    #pragma unroll
    for (int y = Y0; y <= Y1; y++) {
        if (y == Y0) {
            #pragma unroll
            for (int rr = Y0 - 1; rr <= Y0 + 1; rr++)
                if (rr >= 0 && rr <= 5) {
                    #pragma unroll
                    for (int x = 0; x < 6; x++)
                        R[rr % 3][x] =
                            *(const h8*)&LDSH[sA1 + (rr * 6 + x) * 16 + kho];
                }
        } else if (y + 1 <= 5) {
            #pragma unroll
            for (int x = 0; x < 6; x++)
                R[(y + 1) % 3][x] =
                    *(const h8*)&LDSH[sA1 + ((y + 1) * 6 + x) * 16 + kho];
        }
        f32x4 acc[6];
        #pragma unroll
        for (int x = 0; x < 6; x++) acc[x] = ZERO4;
        #pragma unroll
        for (int dy = -1; dy <= 1; dy++) {
            const int ry = y + dy;
            if (ry < 0 || ry > 5) continue;
            const int slot = ry % 3;
            #pragma unroll
            for (int x = 0; x < 6; x++)
                #pragma unroll
                for (int dx = -1; dx <= 1; dx++) {
                    const int sx = x + dx;
                    if (sx < 0 || sx > 5) continue;
                    acc[x] = MFMA16(R[slot][sx],
                                    W2r[(dy + 1) * 3 + (dx + 1)], acc[x]);
                }
        }
        const int pi = (y >> 1) - (Y0 >> 1);
        #pragma unroll
        for (int px = 0; px < 3; px++)
            #pragma unroll
            for (int xx = 0; xx < 2; xx++)
                #pragma unroll
                for (int r = 0; r < 4; r++)
                    pooled2[pi * 3 + px][r] =
                        fmaxf(pooled2[pi * 3 + px][r], acc[px * 2 + xx][r] + b2v);
    }
}

__global__ __launch_bounds__(256, 6) void k_fused(
    const float* __restrict__ board,
    const float* __restrict__ b1, const float* __restrict__ b2,
    const float* __restrict__ b3, const float* __restrict__ qp,
    const unsigned short* __restrict__ w1f,
    const unsigned short* __restrict__ w2f,
    const unsigned short* __restrict__ w3f,
    const unsigned short* __restrict__ w1hd,
    const unsigned short* __restrict__ w2hd,
    const unsigned short* __restrict__ w3hd,
    const float* __restrict__ ptb1, const float* __restrict__ ptb2,
    const float* __restrict__ ptb3, const float* __restrict__ cfb1,
    const float* __restrict__ cfb2,
    float* __restrict__ out)
{
    __shared__ __align__(16) unsigned short LDSH[LDSTOT];
    const int tid = threadIdx.x, wid = tid >> 6, lane = tid & 63;
    const int col = lane & 15, q = lane >> 4;
    const long long gg0 = (long long)blockIdx.x * 16;
    const f32x4 ZERO4 = {0.f, 0.f, 0.f, 0.f};
    unsigned short* Hb = LDSH + H_OFF;
    float* O = (float*)(LDSH + O_OFF);

    // ---- 1. zero BD (pad safety) ----
    for (int e = tid; e < 1040; e += 256)
        ((unsigned long long*)LDSH)[2336 + e] = 0ULL;   // hw 9344..13504
    __syncthreads();

    // ---- 2. stage board fp32 -> fp16, ch-pad-4, pos-pad 8x8 ----
    for (int e = tid; e < 16 * 108; e += 256) {
        int ss = e / 108, r2 = e % 108, ch = r2 / 36, p = r2 % 36;
        float v = board[gg0 * 108 + e];
        LDSH[BD_OFF + ss * BDS4 + ((p / 6 + 1) * 8 + (p % 6) + 1) * 4 + ch] =
            f2h(v);
    }
    __syncthreads();

    // ---- 3. quantum -> register ----
    float qv = 0.f;
    if (tid < 128) {
        int ss = tid >> 3, qq = tid & 7;
        int base = BD_OFF + ss * BDS4;
        int p8a = ((qq / 6 + 1) * 8 + (qq % 6) + 1) * 4;
        int e2 = (qq + 1) & 7;
        int p8b = ((e2 / 6 + 1) * 8 + (e2 % 6) + 1) * 4;
        float xq = h2f(LDSH[base + p8a]);
        float xn = h2f(LDSH[base + p8b]);
        float st = 0.f;
        for (int l = 0; l < 3; l++) {
            float a0 = qp[l * 24 + qq * 3], a1 = qp[l * 24 + qq * 3 + 1],
                  a2 = qp[l * 24 + qq * 3 + 2];
            st = __sinf(a0 * xq) * __cosf(a1 * xn) + tanhf(a2 * st);
        }
        qv = st;
    }

    // ---- 4. conv1: 9 positions per wave ----
    {
        h8 w1r0 = ((const h8*)w1f)[lane];
        h8 w1r1 = ((const h8*)w1f)[64 + lane];
        float b1v = b1[col];
        const int bs = BD_OFF + col * BDS4;
        const int rsel = q >> 1, wo = (q & 1) * 8;
        for (int p = wid * 9; p < wid * 9 + 9; p++) {
            int y = p / 6, x = p % 6;
            int ab1 = bs + ((y + rsel) * 8 + x) * 4 + wo;
            int ab2 = bs + ((y + 2) * 8 + x) * 4 + wo;
            union { h8 v; h4 h[2]; } a1v, a2v;
            a1v.h[0] = *(const h4*)&LDSH[ab1];
            a1v.h[1] = *(const h4*)&LDSH[ab1 + 4];
            a2v.h[0] = *(const h4*)&LDSH[ab2];
            a2v.h[1] = *(const h4*)&LDSH[ab2 + 4];
            f32x4 c = MFMA16(a1v.v, w1r0, ZERO4);
            c = MFMA16(a2v.v, w1r1, c);
            #pragma unroll
            for (int r = 0; r < 4; r++)
                LDSH[(q * 4 + r) * A1S + p * 16 + col] =
                    f2h(fmaxf(c[r] + b1v, 0.f));
        }
    }
    __syncthreads();

    // ---- 5. conv2: (ot = wid&1, y-range = wid>>1 ? 4..5 : 0..3) ----
    const int ot = wid & 1, yh = wid >> 1;
    f32x4 pooled2[6];
    #pragma unroll
    for (int i = 0; i < 6; i++) pooled2[i] = ZERO4;
    {
        h8 W2r[9];
        #pragma unroll
        for (int t = 0; t < 9; t++)
            W2r[t] = ((const h8*)w2f)[(t * 2 + ot) * 64 + lane];
        float b2v = b2[ot * 16 + col];
        if (yh == 0) conv2_sweep<0, 0, 3>(LDSH, W2r, b2v, q, col, pooled2);
        else         conv2_sweep<1, 4, 5>(LDSH, W2r, b2v, q, col, pooled2);
    }
    __syncthreads();   // all A1 reads done before A2 overlays
    {
        const int pr0 = (yh == 0) ? 0 : 2, npr = (yh == 0) ? 2 : 1;
        for (int pi = 0; pi < npr; pi++)
            #pragma unroll
            for (int px = 0; px < 3; px++)
                #pragma unroll
                for (int r = 0; r < 4; r++)
                    LDSH[(q * 4 + r) * A2S + ((pr0 + pi) * 3 + px) * 32 +
                         ot * 16 + col] = f2h(pooled2[pi * 3 + px][r]);
    }
    __syncthreads();

    // ---- 6. conv3 -> registers: (otp = wid&1, pos 0..4 | 5..8) ----
    const int otp = wid & 1, ph = wid >> 1;
    const int P0 = ph ? 5 : 0, NP3 = ph ? 4 : 5;
    f32x4 c3a[5], c3b[5];
    {
        const int sA2 = col * A2S;
        h8 W3r[18];
        #pragma unroll
        for (int f = 0; f < 18; f++)
            W3r[f] = ((const h8*)w3f)[(otp * 18 + f) * 64 + lane];
        for (int pi = 0; pi < 5; pi++) {
            if (pi >= NP3) break;
            const int p = P0 + pi;
            const int y = p / 3, x = p % 3;
            f32x4 acc0 = ZERO4, acc1 = ZERO4;
            #pragma unroll
            for (int t = 0; t < 9; t++) {
                const int sy = y + t / 3 - 1, sx = x + t % 3 - 1;
                if (sy < 0 || sy >= 3 || sx < 0 || sx >= 3) continue;
                h8 a = *(const h8*)&LDSH[sA2 + (sy * 3 + sx) * 32 + q * 8];
                acc0 = MFMA16(a, W3r[t * 2 + 0], acc0);
                acc1 = MFMA16(a, W3r[t * 2 + 1], acc1);
            }
            c3a[pi] = acc0; c3b[pi] = acc1;
        }
    }
    __syncthreads();   // all A2 reads done before FT overlays

    // ---- 7. write FT [p][oc] + quantum + zero tail cols 584..615 ----
    {
        float b3v0 = b3[(otp * 2 + 0) * 16 + col];
        float b3v1 = b3[(otp * 2 + 1) * 16 + col];
        int oc0 = (otp * 2 + 0) * 16 + col, oc1 = (otp * 2 + 1) * 16 + col;
        for (int pi = 0; pi < 5; pi++) {
            if (pi >= NP3) break;
            const int p = P0 + pi;
            #pragma unroll
            for (int r = 0; r < 4; r++) {
                int row = q * 4 + r;
                LDSH[row * FTS + p * 64 + oc0] =
                    f2h(fmaxf(c3a[pi][r] + b3v0, 0.f));
                LDSH[row * FTS + p * 64 + oc1] =
                    f2h(fmaxf(c3b[pi][r] + b3v1, 0.f));
            }
        }
        if (tid < 128) {
            int ss = tid >> 3, qq = tid & 7;
            LDSH[ss * FTS + 576 + qq] = f2h(qv);
        }
        for (int e = tid; e < 512; e += 256)
            LDSH[(e >> 5) * FTS + 584 + (e & 31)] = 0;
    }
    __syncthreads();

    // ---- 8. heads L1: 19 kk, wave does nt-tiles wid*3..+2 ----
    {
        f32x4 acc[3];
        #pragma unroll
        for (int nt = 0; nt < 3; nt++) acc[nt] = ZERO4;
        const h8* wp1 = (const h8*)w1hd;
        const int ntb = wid * 3;
        for (int kk = 0; kk < 19; kk++) {
            h8 a0 = *(const h8*)&LDSH[col * FTS + kk * 32 + q * 8];
            h8 b[3];
            #pragma unroll
            for (int nt = 0; nt < 3; nt++)
                b[nt] = wp1[(kk * 12 + ntb + nt) * 64 + lane];
            #pragma unroll
            for (int nt = 0; nt < 3; nt++)
                acc[nt] = MFMA16(a0, b[nt], acc[nt]);
        }
        #pragma unroll
        for (int nt = 0; nt < 3; nt++) {
            int ntg = ntb + nt;
            float bv = (ntg < 8) ? ptb1[ntg * 16 + col] : cfb1[(ntg - 8) * 16 + col];
            #pragma unroll
            for (int r = 0; r < 4; r++)
                Hb[(q * 4 + r) * HSH + ntg * 16 + col] =
                    f2h(fmaxf(acc[nt][r] + bv, 0.f));
        }
    }
    __syncthreads();

    // ---- 9. heads L2: nt = wid ----
    {
        f32x4 acc2 = ZERO4;
        const h8* wp2 = (const h8*)w2hd;
        #pragma unroll
        for (int kk = 0; kk < 4; kk++) {
            h8 a = *(const h8*)&Hb[col * HSH + kk * 32 + q * 8];
            h8 b = wp2[(kk * 4 + wid) * 64 + lane];
            acc2 = MFMA16(a, b, acc2);
        }
        __syncthreads();   // all L2 reads done before overwriting cols 0..63
        float bv2 = ptb2[wid * 16 + col];
        #pragma unroll
        for (int r = 0; r < 4; r++)
            Hb[(q * 4 + r) * HSH + wid * 16 + col] =
                f2h(fmaxf(acc2[r] + bv2, 0.f));
    }
    __syncthreads();

    // ---- 10. heads L3 + epilogue: wave 0 ----
    if (wid == 0) {
        f32x4 a3 = ZERO4;
        #pragma unroll
        for (int kk = 0; kk < 4; kk++) {
            int base = (kk < 2) ? kk * 32 : kk * 32 + 64;
            h8 a = *(const h8*)&Hb[col * HSH + base + q * 8];
            h8 b = ((const h8*)w3hd)[kk * 64 + lane];
            a3 = MFMA16(a, b, a3);
        }
        if (col < 3) {
            float bv = (col < 2) ? ptb3[col] : cfb2[0];
            #pragma unroll
            for (int r = 0; r < 4; r++)
                O[(q * 4 + r) * 4 + col] = a3[r] + bv;
        }
        if (lane < 16) {
            float l0 = O[lane * 4 + 0], l1 = O[lane * 4 + 1], l2 = O[lane * 4 + 2];
            float m = fmaxf(l0, l1);
            float e0 = __expf(l0 - m), e1 = __expf(l1 - m);
            float inv = 1.f / (e0 + e1);
            float* op = out + (gg0 + lane) * 3;
            op[0] = e0 * inv;
            op[1] = e1 * inv;
            op[2] = 1.f / (1.f + __expf(-l2));
        }
    }
}

extern "C" void kernel_launch(void* const* d_in, const int* in_sizes, int n_in,
                              void* d_out, int out_size, void* d_ws, size_t ws_size,
                              hipStream_t stream) {
    const float* board = (const float*)d_in[0];
    const float* c1w  = (const float*)d_in[2];
    const float* c1b  = (const float*)d_in[3];
    const float* c2w  = (const float*)d_in[4];
    const float* c2b  = (const float*)d_in[5];
    const float* c3w  = (const float*)d_in[6];
    const float* c3b  = (const float*)d_in[7];
    const float* qp   = (const float*)d_in[8];
    const float* ptw1 = (const float*)d_in[9];
    const float* ptb1 = (const float*)d_in[10];
    const float* ptw2 = (const float*)d_in[11];
    const float* ptb2 = (const float*)d_in[12];
    const float* ptw3 = (const float*)d_in[13];
    const float* ptb3 = (const float*)d_in[14];
    const float* cfw1 = (const float*)d_in[15];
    const float* cfb1 = (const float*)d_in[16];
    const float* cfw2 = (const float*)d_in[17];
    const float* cfb2 = (const float*)d_in[18];
    float* out = (float*)d_out;

    int Btot = in_sizes[0] / 108;          // 65536

    unsigned short* w1f   = (unsigned short*)d_ws;
    unsigned short* w2f   = (unsigned short*)((char*)d_ws + 2048);
    unsigned short* w3f   = (unsigned short*)((char*)d_ws + 20480);
    unsigned short* w1hd  = (unsigned short*)((char*)d_ws + 57344);
    unsigned short* w2hd  = (unsigned short*)((char*)d_ws + 290816);
    unsigned short* w3hd  = (unsigned short*)((char*)d_ws + 307200);

    hipLaunchKernelGGL(k_prep, dim3(256), dim3(256), 0, stream,
                       c1w, c2w, c3w, ptw1, cfw1, ptw2, ptw3, cfw2,
                       w1f, w2f, w3f, w1hd, w2hd, w3hd);
    hipLaunchKernelGGL(k_fused, dim3(Btot / 16), dim3(256), 0, stream,
                       board, c1b, c2b, c3b, qp, w1f, w2f, w3f,
                       w1hd, w2hd, w3hd, ptb1, ptb2, ptb3, cfb1, cfb2, out);
}